// Round 1
// baseline (221.019 us; speedup 1.0000x reference)
//
#include <hip/hip_runtime.h>
#include <stdint.h>

// Problem constants (input: float32 (16, 37, 224, 224), label = 1)
#define NB 16
#define NC 37
#define H 224
#define W 224
#define HW (H * W)                     // 50176
#define WPR 7                          // 32-bit mask words per row (224 = 7*32 exactly)
#define IMG_WORDS (H * WPR)            // 1568
#define QUADS_PER_IMG (HW / 4)         // 12544
#define BLOCKS_PER_IMG (QUADS_PER_IMG / 256)  // 49 -> blocks never straddle images

// ---------------------------------------------------------------------------
// K1: channel argmax (first-max tie-break, matching jnp.argmax) + per-image
// label max via atomics. Writes labels as uint8 (values 0..36).
// ---------------------------------------------------------------------------
__global__ __launch_bounds__(256) void k_argmax(const float* __restrict__ in,
                                                uint8_t* __restrict__ lab,
                                                int* __restrict__ maxv) {
    const int b = blockIdx.x / BLOCKS_PER_IMG;
    const int qid = blockIdx.x * 256 + threadIdx.x;      // global quad id
    const int p = (qid % QUADS_PER_IMG) * 4;             // pixel within image
    const float4* base = (const float4*)(in + (size_t)b * NC * HW + p);
    float4 bv = base[0];
    int ix = 0, iy = 0, iz = 0, iw = 0;
    for (int c = 1; c < NC; ++c) {
        float4 v = base[(size_t)c * (HW / 4)];
        if (v.x > bv.x) { bv.x = v.x; ix = c; }
        if (v.y > bv.y) { bv.y = v.y; iy = c; }
        if (v.z > bv.z) { bv.z = v.z; iz = c; }
        if (v.w > bv.w) { bv.w = v.w; iw = c; }
    }
    uint32_t packed = (uint32_t)ix | ((uint32_t)iy << 8) |
                      ((uint32_t)iz << 16) | ((uint32_t)iw << 24);
    *(uint32_t*)(lab + (size_t)b * HW + p) = packed;

    int mymax = max(max(ix, iy), max(iz, iw));
    __shared__ int smax;
    if (threadIdx.x == 0) smax = 0;
    __syncthreads();
    atomicMax(&smax, mymax);
    __syncthreads();
    if (threadIdx.x == 0) atomicMax(&maxv[b], smax);
}

// ---------------------------------------------------------------------------
// K2: quantize (37-entry LUT, bit-identical float op sequence to XLA) +
// 5x5 blur as exact integer conv (S = sum k_i k_j q), threshold S >= 129
// (== round-half-even(S/256) > 0). Packs mask bits via wave shuffles.
// ---------------------------------------------------------------------------
__global__ __launch_bounds__(256) void k_mask(const uint8_t* __restrict__ lab,
                                              const int* __restrict__ maxv,
                                              uint32_t* __restrict__ mbits) {
    __shared__ int qlut[NC];
    const int tid = threadIdx.x;
    const int b = blockIdx.x / BLOCKS_PER_IMG;
    if (tid < NC) {
        int mv = maxv[b];
        // identical op order to reference: floor(255.0f * (l / maxv))
        qlut[tid] = (mv > 0) ? (int)floorf(255.0f * ((float)tid / (float)mv)) : 0;
    }
    __syncthreads();

    const int qid = blockIdx.x * 256 + tid;
    const int rem = qid % QUADS_PER_IMG;
    const int h = rem / (W / 4);
    const int w0 = (rem % (W / 4)) * 4;
    const uint8_t* __restrict__ L = lab + (size_t)b * HW;

    int S0 = 0, S1 = 0, S2 = 0, S3 = 0;
    const int kw[5] = {1, 4, 6, 4, 1};
#pragma unroll
    for (int i = 0; i < 5; ++i) {
        int r = h + i - 2;                       // reflect-101 row mirror
        r = (r < 0) ? -r : ((r > H - 1) ? (2 * (H - 1) - r) : r);
        const uint8_t* row = L + r * W;
        int q0, q1, q2, q3, q4, q5, q6, q7;      // q at cols w0-2 .. w0+5
        if (w0 >= 4 && w0 <= W - 8) {            // interior: 3 aligned word loads
            uint32_t wa = *(const uint32_t*)(row + w0 - 4);
            uint32_t wb = *(const uint32_t*)(row + w0);
            uint32_t wc = *(const uint32_t*)(row + w0 + 4);
            q0 = qlut[(wa >> 16) & 0xff];
            q1 = qlut[(wa >> 24) & 0xff];
            q2 = qlut[wb & 0xff];
            q3 = qlut[(wb >> 8) & 0xff];
            q4 = qlut[(wb >> 16) & 0xff];
            q5 = qlut[(wb >> 24) & 0xff];
            q6 = qlut[wc & 0xff];
            q7 = qlut[(wc >> 8) & 0xff];
        } else {                                 // edge quads: mirrored byte loads
            int qq[8];
#pragma unroll
            for (int t = 0; t < 8; ++t) {
                int wc2 = w0 - 2 + t;
                wc2 = (wc2 < 0) ? -wc2 : ((wc2 > W - 1) ? (2 * (W - 1) - wc2) : wc2);
                qq[t] = qlut[row[wc2]];
            }
            q0 = qq[0]; q1 = qq[1]; q2 = qq[2]; q3 = qq[3];
            q4 = qq[4]; q5 = qq[5]; q6 = qq[6]; q7 = qq[7];
        }
        int sh0 = q0 + 4 * q1 + 6 * q2 + 4 * q3 + q4;
        int sh1 = q1 + 4 * q2 + 6 * q3 + 4 * q4 + q5;
        int sh2 = q2 + 4 * q3 + 6 * q4 + 4 * q5 + q6;
        int sh3 = q3 + 4 * q4 + 6 * q5 + 4 * q6 + q7;
        int k = kw[i];
        S0 += k * sh0; S1 += k * sh1; S2 += k * sh2; S3 += k * sh3;
    }
    uint32_t nib = (S0 > 128 ? 1u : 0u) | (S1 > 128 ? 2u : 0u) |
                   (S2 > 128 ? 4u : 0u) | (S3 > 128 ? 8u : 0u);
    // pack 8 lanes' nibbles (8 quads = 32 pixels) into one word
    uint32_t wword = nib << ((tid & 7) * 4);
    wword |= __shfl_xor(wword, 1);
    wword |= __shfl_xor(wword, 2);
    wword |= __shfl_xor(wword, 4);
    if ((tid & 7) == 0) mbits[qid >> 3] = wword;  // qid/8 == b*1568 + h*7 + w0/32
}

// ---------------------------------------------------------------------------
// K3: per-image (grid=16): opening (erode pad=True, dilate pad=False) then
// hole fill = flood of ~opened from border (4-conn), fg = ~bg. Bitmask LDS.
// ---------------------------------------------------------------------------
__global__ __launch_bounds__(256) void k_morph_fill(const uint32_t* __restrict__ mbits,
                                                    uint32_t* __restrict__ fg) {
    const int b = blockIdx.x;
    const int tid = threadIdx.x;
    __shared__ uint32_t A[IMG_WORDS];   // mask -> opened mask
    __shared__ uint32_t Bw[IMG_WORDS];  // erode temp -> flood state
    __shared__ int s_changed;

    const uint32_t* src = mbits + b * IMG_WORDS;
    for (int i = tid; i < IMG_WORDS; i += 256) A[i] = src[i];
    __syncthreads();

    // erode (out-of-image = True)
    for (int i = tid; i < IMG_WORDS; i += 256) {
        int h = i / WPR, k = i % WPR;
        uint32_t cur = A[i];
        uint32_t north = (h > 0) ? A[i - WPR] : 0xFFFFFFFFu;
        uint32_t south = (h < H - 1) ? A[i + WPR] : 0xFFFFFFFFu;
        uint32_t west = (cur << 1) | ((k > 0) ? (A[i - 1] >> 31) : 1u);
        uint32_t east = (cur >> 1) | ((k < WPR - 1) ? (A[i + 1] << 31) : 0x80000000u);
        Bw[i] = cur & north & south & west & east;
    }
    __syncthreads();
    // dilate (out-of-image = False) -> opened into A
    for (int i = tid; i < IMG_WORDS; i += 256) {
        int h = i / WPR, k = i % WPR;
        uint32_t cur = Bw[i];
        uint32_t north = (h > 0) ? Bw[i - WPR] : 0u;
        uint32_t south = (h < H - 1) ? Bw[i + WPR] : 0u;
        uint32_t west = (cur << 1) | ((k > 0) ? (Bw[i - 1] >> 31) : 0u);
        uint32_t east = (cur >> 1) | ((k < WPR - 1) ? (Bw[i + 1] << 31) : 0u);
        A[i] = cur | north | south | west | east;
    }
    __syncthreads();
    // flood seed: Bw = comp & border   (comp = ~opened; seeds always subset of comp)
    for (int i = tid; i < IMG_WORDS; i += 256) {
        int h = i / WPR, k = i % WPR;
        uint32_t comp = ~A[i];
        uint32_t border = (h == 0 || h == H - 1)
                              ? 0xFFFFFFFFu
                              : (((k == 0) ? 1u : 0u) | ((k == WPR - 1) ? 0x80000000u : 0u));
        Bw[i] = comp & border;
    }
    __syncthreads();

    // flood to fixpoint: vertical sweeps (32 cols/word in parallel) + row sweeps
    while (true) {
        if (tid == 0) s_changed = 0;
        __syncthreads();
        // vertical: thread per word-column (7 of them), down then up
        if (tid < WPR) {
            const int k = tid;
            uint32_t carry = 0;
            for (int h = 0; h < H; ++h) {
                int i = h * WPR + k;
                uint32_t comp = ~A[i];
                uint32_t s = Bw[i];
                uint32_t ns = comp & (s | carry);
                if (ns != s) { Bw[i] = ns; s_changed = 1; }
                carry = ns;
            }
            carry = 0;
            for (int h = H - 1; h >= 0; --h) {
                int i = h * WPR + k;
                uint32_t comp = ~A[i];
                uint32_t s = Bw[i];
                uint32_t ns = comp & (s | carry);
                if (ns != s) { Bw[i] = ns; s_changed = 1; }
                carry = ns;
            }
        }
        __syncthreads();
        // horizontal: thread per row, L2R then R2L bit scans
        if (tid < H) {
            const int base = tid * WPR;
            bool carry = false;
            for (int k = 0; k < WPR; ++k) {
                uint32_t comp = ~A[base + k];
                uint32_t s = Bw[base + k];
                if (comp == 0) { carry = false; continue; }
                if (!carry && s == 0) { continue; }
                uint32_t nb = 0;
                for (int bp = 0; bp < 32; ++bp) {
                    uint32_t m = 1u << bp;
                    if (!(comp & m)) carry = false;
                    else if (s & m) carry = true;
                    else if (carry) nb |= m;
                }
                if (nb) { Bw[base + k] = s | nb; s_changed = 1; }
            }
            carry = false;
            for (int k = WPR - 1; k >= 0; --k) {
                uint32_t comp = ~A[base + k];
                uint32_t s = Bw[base + k];
                if (comp == 0) { carry = false; continue; }
                if (!carry && s == 0) { continue; }
                uint32_t nb = 0;
                for (int bp = 31; bp >= 0; --bp) {
                    uint32_t m = 1u << bp;
                    if (!(comp & m)) carry = false;
                    else if (s & m) carry = true;
                    else if (carry) nb |= m;
                }
                if (nb) { Bw[base + k] = s | nb; s_changed = 1; }
            }
        }
        __syncthreads();
        int done = (s_changed == 0);
        __syncthreads();
        if (done) break;
    }

    uint32_t* dst = fg + b * IMG_WORDS;
    for (int i = tid; i < IMG_WORDS; i += 256) dst[i] = ~Bw[i];  // fg = ~bg
}

// ---------------------------------------------------------------------------
// K4: expand fg bitmask to float32 (16, 3, 224, 224) output, float4 stores.
// ---------------------------------------------------------------------------
__global__ __launch_bounds__(256) void k_expand(const uint32_t* __restrict__ fg,
                                                float* __restrict__ out) {
    const int qid = blockIdx.x * 256 + threadIdx.x;  // 602112 quads total
    if (qid >= NB * 3 * H * (W / 4)) return;
    const int wq = qid % (W / 4);
    const int t = qid / (W / 4);
    const int h = t % H;
    const int t2 = t / H;     // b*3 + c
    const int b = t2 / 3;
    uint32_t word = fg[b * IMG_WORDS + h * WPR + (wq >> 3)];
    const int sh = (wq & 7) * 4;
    float4 v;
    v.x = ((word >> sh) & 1u) ? 1.0f : 0.0f;
    v.y = ((word >> (sh + 1)) & 1u) ? 1.0f : 0.0f;
    v.z = ((word >> (sh + 2)) & 1u) ? 1.0f : 0.0f;
    v.w = ((word >> (sh + 3)) & 1u) ? 1.0f : 0.0f;
    ((float4*)out)[qid] = v;
}

// ---------------------------------------------------------------------------
extern "C" void kernel_launch(void* const* d_in, const int* in_sizes, int n_in,
                              void* d_out, int out_size, void* d_ws, size_t ws_size,
                              hipStream_t stream) {
    const float* in = (const float*)d_in[0];   // (16,37,224,224) float32
    float* out = (float*)d_out;                // (16,3,224,224) float32

    // workspace layout (total ~1 MB)
    uint8_t* lab = (uint8_t*)d_ws;                                // 802816 B
    int* maxv = (int*)((char*)d_ws + 802816);                     // 64 B
    uint32_t* mbits = (uint32_t*)((char*)d_ws + 802880);          // 100352 B
    uint32_t* fgb = (uint32_t*)((char*)d_ws + 903232);            // 100352 B

    hipMemsetAsync(maxv, 0, NB * sizeof(int), stream);
    k_argmax<<<NB * BLOCKS_PER_IMG, 256, 0, stream>>>(in, lab, maxv);
    k_mask<<<NB * BLOCKS_PER_IMG, 256, 0, stream>>>(lab, maxv, mbits);
    k_morph_fill<<<NB, 256, 0, stream>>>(mbits, fgb);
    k_expand<<<(NB * 3 * H * (W / 4) + 255) / 256, 256, 0, stream>>>(fgb, out);
}